// Round 1
// baseline (980.767 us; speedup 1.0000x reference)
//
#include <hip/hip_runtime.h>
#include <hip/hip_bf16.h>

#define BATCH 8
#define CDIM 192
#define HEADS 8
#define CH 24
#define HH 128
#define WW 128
#define NPIX (HH*WW)                  // 16384
#define NELEM (BATCH*CDIM*NPIX)       // 25165824

#define NSLAB 32
#define SLAB (NPIX/NSLAB)             // 512
#define NJOBS 624                     // 576 cross dots + 24 q self + 24 k self

// Static device scratch (avoids depending on ws_size).
__device__ float g_t0[NELEM];
__device__ float g_q[NELEM];
__device__ float g_k[NELEM];
__device__ float g_v[NELEM];
__device__ float g_part[64 * NSLAB * NJOBS];
__device__ float g_S[64 * NJOBS];
__device__ float g_M[BATCH * CDIM * CDIM];

// ---------------------------------------------------------------------------
// Pointwise GEMM: Out[b,o,p] = sum_c W[o,c] * X[b,c,p]
// W row-major [192][192]; wstride_b = 0 for shared weights, 192*192 for
// per-batch weights (the fused attn+proj matrix M_b).
// Tile: BM=64 (out ch) x BN=128 (pixels), BK=32, 256 threads, 4x8 micro-tile.
// ---------------------------------------------------------------------------
#define BM 64
#define BN 128
#define BK 32

__global__ __launch_bounds__(256) void pw_gemm(const float* __restrict__ X,
                                               const float* __restrict__ Wt,
                                               int wstride_b,
                                               float* __restrict__ Out) {
  const int bn = blockIdx.x;   // 0..127
  const int bm = blockIdx.y;   // 0..2
  const int b  = blockIdx.z;   // 0..7
  const float* Xb = X + (size_t)b * CDIM * NPIX;
  float* Ob       = Out + (size_t)b * CDIM * NPIX;
  const float* Wb = Wt + (size_t)b * wstride_b;

  __shared__ float As[BK][BM];   // As[k][m] = W[bm*64+m][k0+k]
  __shared__ float Bs[BK][BN];   // Bs[k][n] = X[k0+k][bn*128+n]

  const int t = threadIdx.x;
  const int tn = t & 15;   // 0..15 -> 8 pixels each
  const int tm = t >> 4;   // 0..15 -> 4 out-ch each

  float acc[4][8];
#pragma unroll
  for (int i = 0; i < 4; ++i)
#pragma unroll
    for (int j = 0; j < 8; ++j) acc[i][j] = 0.f;

  for (int k0 = 0; k0 < CDIM; k0 += BK) {
    // Load A tile (64x32): thread t loads 8 contiguous c of row o=t>>2
    {
      const int o = t >> 2;
      const int c = (t & 3) * 8;
      const float* src = Wb + (size_t)(bm * BM + o) * CDIM + k0 + c;
#pragma unroll
      for (int j = 0; j < 8; ++j) As[c + j][o] = src[j];
    }
    // Load B tile (32x128): 4 float4 per thread
    {
      const int col4 = (t & 31) * 4;
      const int r0 = t >> 5;
#pragma unroll
      for (int p = 0; p < 4; ++p) {
        const int r = r0 + p * 8;
        const float4 val =
            *(const float4*)(Xb + (size_t)(k0 + r) * NPIX + bn * BN + col4);
        *(float4*)&Bs[r][col4] = val;
      }
    }
    __syncthreads();
#pragma unroll
    for (int kk = 0; kk < BK; ++kk) {
      const float4 a  = *(const float4*)&As[kk][tm * 4];
      const float4 b0 = *(const float4*)&Bs[kk][tn * 8];
      const float4 b1 = *(const float4*)&Bs[kk][tn * 8 + 4];
      const float av[4] = {a.x, a.y, a.z, a.w};
      const float bv[8] = {b0.x, b0.y, b0.z, b0.w, b1.x, b1.y, b1.z, b1.w};
#pragma unroll
      for (int i = 0; i < 4; ++i)
#pragma unroll
        for (int j = 0; j < 8; ++j) acc[i][j] += av[i] * bv[j];
    }
    __syncthreads();
  }

#pragma unroll
  for (int i = 0; i < 4; ++i) {
    const int o = bm * BM + tm * 4 + i;
    float* dst = Ob + (size_t)o * NPIX + bn * BN + tn * 8;
#pragma unroll
    for (int j = 0; j < 8; ++j) dst[j] = acc[i][j];
  }
}

// ---------------------------------------------------------------------------
// Depthwise 3x3 conv, zero pad. One float4 of output per thread.
// Wd layout: [C][1][3][3] -> Wd[c*9 + (dy)*3 + dx]
// ---------------------------------------------------------------------------
__global__ __launch_bounds__(256) void dwconv(const float* __restrict__ In,
                                              const float* __restrict__ Wd,
                                              float* __restrict__ Out) {
  const int idx = blockIdx.x * 256 + threadIdx.x;   // 0 .. NELEM/4-1
  if (idx >= NELEM / 4) return;
  const int x4 = (idx & 31) * 4;           // 0..124
  const int y  = (idx >> 5) & 127;
  const int c  = (idx >> 12) % CDIM;
  const int b  = idx / (32 * 128 * CDIM);

  const float* base = In + (size_t)(b * CDIM + c) * NPIX;
  float w[9];
#pragma unroll
  for (int i = 0; i < 9; ++i) w[i] = Wd[c * 9 + i];

  float acc0 = 0.f, acc1 = 0.f, acc2 = 0.f, acc3 = 0.f;
#pragma unroll
  for (int dy = 0; dy < 3; ++dy) {
    const int yy = y + dy - 1;
    if (yy < 0 || yy > 127) continue;
    const float* row = base + yy * WW;
    float vb0 = (x4 > 0) ? row[x4 - 1] : 0.f;
    const float4 m = *(const float4*)(row + x4);
    const float vb5 = (x4 + 4 < WW) ? row[x4 + 4] : 0.f;
    const float w0 = w[dy * 3 + 0], w1 = w[dy * 3 + 1], w2 = w[dy * 3 + 2];
    acc0 += w0 * vb0 + w1 * m.x + w2 * m.y;
    acc1 += w0 * m.x + w1 * m.y + w2 * m.z;
    acc2 += w0 * m.y + w1 * m.z + w2 * m.w;
    acc3 += w0 * m.z + w1 * m.w + w2 * vb5;
  }
  float4 o;
  o.x = acc0; o.y = acc1; o.z = acc2; o.w = acc3;
  *(float4*)(Out + (size_t)idx * 4) = o;
}

// ---------------------------------------------------------------------------
// Gram dots (q.k cross, q.q and k.k self) with n-slab partials (deterministic,
// no float atomics). Grid (64 bh, 32 slabs), 256 threads.
// ---------------------------------------------------------------------------
__global__ __launch_bounds__(256) void dots_partial(const float* __restrict__ Q,
                                                    const float* __restrict__ K,
                                                    float* __restrict__ Part) {
  const int bh = blockIdx.x;     // b*8+h
  const int slab = blockIdx.y;   // 0..31
  const int b = bh >> 3, h = bh & 7;
  __shared__ float qs[CH][SLAB];
  __shared__ float ks[CH][SLAB];
  const int t = threadIdx.x;

  for (int i = t; i < CH * (SLAB / 4); i += 256) {
    const int r = i >> 7;             // SLAB/4 = 128
    const int c4 = (i & 127) << 2;
    const size_t off = (size_t)(b * CDIM + h * CH + r) * NPIX + slab * SLAB + c4;
    *(float4*)&qs[r][c4] = *(const float4*)&Q[off];
    *(float4*)&ks[r][c4] = *(const float4*)&K[off];
  }
  __syncthreads();

  for (int job = t; job < NJOBS; job += 256) {
    const float* A;
    const float* Bp;
    if (job < 576)      { A = qs[job / 24]; Bp = ks[job % 24]; }
    else if (job < 600) { A = qs[job - 576]; Bp = qs[job - 576]; }
    else                { A = ks[job - 600]; Bp = ks[job - 600]; }
    float s = 0.f;
    for (int n = 0; n < SLAB; n += 4) {
      const float4 a  = *(const float4*)&A[n];
      const float4 bb = *(const float4*)&Bp[n];
      s += a.x * bb.x + a.y * bb.y + a.z * bb.z + a.w * bb.w;
    }
    Part[((size_t)bh * NSLAB + slab) * NJOBS + job] = s;
  }
}

__global__ __launch_bounds__(640) void dots_reduce(const float* __restrict__ Part,
                                                   float* __restrict__ S) {
  const int bh = blockIdx.x;
  const int job = threadIdx.x;
  if (job >= NJOBS) return;
  float s = 0.f;
  for (int i = 0; i < NSLAB; ++i)
    s += Part[((size_t)bh * NSLAB + i) * NJOBS + job];
  S[bh * NJOBS + job] = s;
}

// ---------------------------------------------------------------------------
// Normalize logits, softmax, and build per-batch fused matrix
// M_b = proj_w @ blockdiag(attn_b).  Grid (8 batches, 8 heads), 576 threads.
// M[b][o][h*24+d] = sum_c proj_w[o][h*24+c] * attn[b,h,c,d]
// ---------------------------------------------------------------------------
__global__ __launch_bounds__(576) void build_M(const float* __restrict__ S,
                                               const float* __restrict__ PW,
                                               const float* __restrict__ Temp,
                                               float* __restrict__ M) {
  const int b = blockIdx.x, h = blockIdx.y;
  const int bh = b * 8 + h;
  __shared__ float att[CH][CH];
  __shared__ float qn[CH], kn[CH];
  const int t = threadIdx.x;
  const float* Sb = S + (size_t)bh * NJOBS;

  if (t < CH) {
    qn[t] = fmaxf(sqrtf(Sb[576 + t]), 1e-12f);
    kn[t] = fmaxf(sqrtf(Sb[600 + t]), 1e-12f);
  }
  __syncthreads();
  const float temp = Temp[h];
  if (t < 576) {
    const int c = t / 24, d = t % 24;
    att[c][d] = Sb[t] / (qn[c] * kn[d]) * temp;
  }
  __syncthreads();
  if (t < CH) {
    float mx = -1e30f;
    for (int d = 0; d < CH; ++d) mx = fmaxf(mx, att[t][d]);
    float sum = 0.f;
    for (int d = 0; d < CH; ++d) {
      const float e = __expf(att[t][d] - mx);
      att[t][d] = e;
      sum += e;
    }
    const float inv = 1.f / sum;
    for (int d = 0; d < CH; ++d) att[t][d] *= inv;
  }
  __syncthreads();
  for (int i = t; i < CDIM * CH; i += 576) {
    const int o = i / CH, d = i % CH;
    float s = 0.f;
#pragma unroll
    for (int c = 0; c < CH; ++c) s += PW[o * CDIM + h * CH + c] * att[c][d];
    M[((size_t)b * CDIM + o) * CDIM + h * CH + d] = s;
  }
}

// ---------------------------------------------------------------------------

extern "C" void kernel_launch(void* const* d_in, const int* in_sizes, int n_in,
                              void* d_out, int out_size, void* d_ws, size_t ws_size,
                              hipStream_t stream) {
  const float* x_feat = (const float*)d_in[0];
  const float* y_feat = (const float*)d_in[1];
  const float* q_pw   = (const float*)d_in[2];
  const float* q_dw   = (const float*)d_in[3];
  const float* k_pw   = (const float*)d_in[4];
  const float* k_dw   = (const float*)d_in[5];
  const float* v_pw   = (const float*)d_in[6];
  const float* v_dw   = (const float*)d_in[7];
  const float* proj_w = (const float*)d_in[8];
  const float* temp   = (const float*)d_in[9];
  float* out = (float*)d_out;

  float *t0, *q, *k, *v, *part, *S, *M;
  hipGetSymbolAddress((void**)&t0,   HIP_SYMBOL(g_t0));
  hipGetSymbolAddress((void**)&q,    HIP_SYMBOL(g_q));
  hipGetSymbolAddress((void**)&k,    HIP_SYMBOL(g_k));
  hipGetSymbolAddress((void**)&v,    HIP_SYMBOL(g_v));
  hipGetSymbolAddress((void**)&part, HIP_SYMBOL(g_part));
  hipGetSymbolAddress((void**)&S,    HIP_SYMBOL(g_S));
  hipGetSymbolAddress((void**)&M,    HIP_SYMBOL(g_M));

  const dim3 ggrid(NPIX / BN, CDIM / BM, BATCH);  // (128,3,8)
  const int dwgrid = (NELEM / 4) / 256;           // 24576

  // q = dw(pw(x, q_pw), q_dw)
  pw_gemm<<<ggrid, 256, 0, stream>>>(x_feat, q_pw, 0, t0);
  dwconv<<<dwgrid, 256, 0, stream>>>(t0, q_dw, q);
  // k = dw(pw(y, k_pw), k_dw)
  pw_gemm<<<ggrid, 256, 0, stream>>>(y_feat, k_pw, 0, t0);
  dwconv<<<dwgrid, 256, 0, stream>>>(t0, k_dw, k);
  // v = dw(pw(y, v_pw), v_dw)
  pw_gemm<<<ggrid, 256, 0, stream>>>(y_feat, v_pw, 0, t0);
  dwconv<<<dwgrid, 256, 0, stream>>>(t0, v_dw, v);

  // attention gram dots + norms
  dots_partial<<<dim3(64, NSLAB), 256, 0, stream>>>(q, k, part);
  dots_reduce<<<64, 640, 0, stream>>>(part, S);

  // softmax + fold proj into per-batch matrix M_b
  build_M<<<dim3(BATCH, HEADS), 576, 0, stream>>>(S, proj_w, temp, M);

  // out = M_b @ v
  pw_gemm<<<ggrid, 256, 0, stream>>>(v, M, CDIM * CDIM, out);
}

// Round 2
// 739.605 us; speedup vs baseline: 1.3261x; 1.3261x over previous
//
#include <hip/hip_runtime.h>
#include <hip/hip_bf16.h>

#define BATCH 8
#define CDIM 192
#define HEADS 8
#define CH 24
#define HH 128
#define WW 128
#define NPIX (HH*WW)                  // 16384
#define NELEM (BATCH*CDIM*NPIX)       // 25165824

#define NSLAB 16
#define NJOBS 624                     // 576 cross dots + 24 q self + 24 k self

// Static device scratch (avoids depending on ws_size).
__device__ float g_t0[NELEM];
__device__ float g_q[NELEM];
__device__ float g_k[NELEM];
__device__ float g_v[NELEM];
__device__ float g_part[64 * NSLAB * NJOBS];
__device__ float g_S[64 * NJOBS];
__device__ float g_M[BATCH * CDIM * CDIM];

// ---------------------------------------------------------------------------
// Pointwise GEMM: Out[b,o,p] = sum_c W[o,c] * X[b,c,p]
// ---------------------------------------------------------------------------
#define BM 64
#define BN 128
#define BK 32

__global__ __launch_bounds__(256) void pw_gemm(const float* __restrict__ X,
                                               const float* __restrict__ Wt,
                                               int wstride_b,
                                               float* __restrict__ Out) {
  const int bn = blockIdx.x;   // 0..127
  const int bm = blockIdx.y;   // 0..2
  const int b  = blockIdx.z;   // 0..7
  const float* Xb = X + (size_t)b * CDIM * NPIX;
  float* Ob       = Out + (size_t)b * CDIM * NPIX;
  const float* Wb = Wt + (size_t)b * wstride_b;

  __shared__ float As[BK][BM];   // As[k][m] = W[bm*64+m][k0+k]
  __shared__ float Bs[BK][BN];   // Bs[k][n] = X[k0+k][bn*128+n]

  const int t = threadIdx.x;
  const int tn = t & 15;   // 0..15 -> 8 pixels each
  const int tm = t >> 4;   // 0..15 -> 4 out-ch each

  float acc[4][8];
#pragma unroll
  for (int i = 0; i < 4; ++i)
#pragma unroll
    for (int j = 0; j < 8; ++j) acc[i][j] = 0.f;

  for (int k0 = 0; k0 < CDIM; k0 += BK) {
    {
      const int o = t >> 2;
      const int c = (t & 3) * 8;
      const float* src = Wb + (size_t)(bm * BM + o) * CDIM + k0 + c;
#pragma unroll
      for (int j = 0; j < 8; ++j) As[c + j][o] = src[j];
    }
    {
      const int col4 = (t & 31) * 4;
      const int r0 = t >> 5;
#pragma unroll
      for (int p = 0; p < 4; ++p) {
        const int r = r0 + p * 8;
        const float4 val =
            *(const float4*)(Xb + (size_t)(k0 + r) * NPIX + bn * BN + col4);
        *(float4*)&Bs[r][col4] = val;
      }
    }
    __syncthreads();
#pragma unroll
    for (int kk = 0; kk < BK; ++kk) {
      const float4 a  = *(const float4*)&As[kk][tm * 4];
      const float4 b0 = *(const float4*)&Bs[kk][tn * 8];
      const float4 b1 = *(const float4*)&Bs[kk][tn * 8 + 4];
      const float av[4] = {a.x, a.y, a.z, a.w};
      const float bv[8] = {b0.x, b0.y, b0.z, b0.w, b1.x, b1.y, b1.z, b1.w};
#pragma unroll
      for (int i = 0; i < 4; ++i)
#pragma unroll
        for (int j = 0; j < 8; ++j) acc[i][j] += av[i] * bv[j];
    }
    __syncthreads();
  }

#pragma unroll
  for (int i = 0; i < 4; ++i) {
    const int o = bm * BM + tm * 4 + i;
    float* dst = Ob + (size_t)o * NPIX + bn * BN + tn * 8;
#pragma unroll
    for (int j = 0; j < 8; ++j) dst[j] = acc[i][j];
  }
}

// ---------------------------------------------------------------------------
// Depthwise 3x3 conv, zero pad. One float4 of output per thread.
// ---------------------------------------------------------------------------
__global__ __launch_bounds__(256) void dwconv(const float* __restrict__ In,
                                              const float* __restrict__ Wd,
                                              float* __restrict__ Out) {
  const int idx = blockIdx.x * 256 + threadIdx.x;   // 0 .. NELEM/4-1
  if (idx >= NELEM / 4) return;
  const int x4 = (idx & 31) * 4;           // 0..124
  const int y  = (idx >> 5) & 127;
  const int c  = (idx >> 12) % CDIM;
  const int b  = idx / (32 * 128 * CDIM);

  const float* base = In + (size_t)(b * CDIM + c) * NPIX;
  float w[9];
#pragma unroll
  for (int i = 0; i < 9; ++i) w[i] = Wd[c * 9 + i];

  float acc0 = 0.f, acc1 = 0.f, acc2 = 0.f, acc3 = 0.f;
#pragma unroll
  for (int dy = 0; dy < 3; ++dy) {
    const int yy = y + dy - 1;
    if (yy < 0 || yy > 127) continue;
    const float* row = base + yy * WW;
    float vb0 = (x4 > 0) ? row[x4 - 1] : 0.f;
    const float4 m = *(const float4*)(row + x4);
    const float vb5 = (x4 + 4 < WW) ? row[x4 + 4] : 0.f;
    const float w0 = w[dy * 3 + 0], w1 = w[dy * 3 + 1], w2 = w[dy * 3 + 2];
    acc0 += w0 * vb0 + w1 * m.x + w2 * m.y;
    acc1 += w0 * m.x + w1 * m.y + w2 * m.z;
    acc2 += w0 * m.y + w1 * m.z + w2 * m.w;
    acc3 += w0 * m.z + w1 * m.w + w2 * vb5;
  }
  float4 o;
  o.x = acc0; o.y = acc1; o.z = acc2; o.w = acc3;
  *(float4*)(Out + (size_t)idx * 4) = o;
}

// ---------------------------------------------------------------------------
// Gram dots v2: register outer-product, no LDS.
// Grid (64 bh, NSLAB slabs), 256 threads.
// Thread (pg = t&15, sb = t>>4): owns 6x6 sub-block (sr,sc)=(sb>>2, sb&3)
// of the 24x24 gram; accumulates over float4 pixel packs pg+16*i.
// q-row reads broadcast within a wave (sr is wave-uniform); k-rows 4-way
// L1-served. Reduce over pg via 16-lane __shfl_xor tree.
// ---------------------------------------------------------------------------
__global__ __launch_bounds__(256) void dots_partial(const float* __restrict__ Q,
                                                    const float* __restrict__ K,
                                                    float* __restrict__ Part) {
  const int bh = blockIdx.x;     // b*8+h
  const int slab = blockIdx.y;   // 0..NSLAB-1
  const int b = bh >> 3, h = bh & 7;
  const int t = threadIdx.x;
  const int pg = t & 15;
  const int sb = t >> 4;
  const int sr = sb >> 2, sc = sb & 3;
  const bool diag = (sr == sc);

  const float4* qb = (const float4*)(Q + (size_t)(b * CDIM + h * CH) * NPIX);
  const float4* kb = (const float4*)(K + (size_t)(b * CDIM + h * CH) * NPIX);
  const int NP4 = NPIX / 4;                 // 4096 float4 per row
  const int F_PER_SLAB = NP4 / NSLAB;       // 256
  const int NITER = F_PER_SLAB / 16;        // 16

  float acc[6][6];
#pragma unroll
  for (int j = 0; j < 6; ++j)
#pragma unroll
    for (int c = 0; c < 6; ++c) acc[j][c] = 0.f;
  float qq[6] = {0, 0, 0, 0, 0, 0};
  float kk[6] = {0, 0, 0, 0, 0, 0};

  const int f0 = slab * F_PER_SLAB + pg;
  for (int i = 0; i < NITER; ++i) {
    const int f = f0 + 16 * i;
    float4 qv[6], kv[6];
#pragma unroll
    for (int j = 0; j < 6; ++j) qv[j] = qb[(size_t)(sr * 6 + j) * NP4 + f];
#pragma unroll
    for (int j = 0; j < 6; ++j) kv[j] = kb[(size_t)(sc * 6 + j) * NP4 + f];
#pragma unroll
    for (int j = 0; j < 6; ++j)
#pragma unroll
      for (int c = 0; c < 6; ++c)
        acc[j][c] += qv[j].x * kv[c].x + qv[j].y * kv[c].y +
                     qv[j].z * kv[c].z + qv[j].w * kv[c].w;
    if (diag) {
#pragma unroll
      for (int j = 0; j < 6; ++j) {
        qq[j] += qv[j].x * qv[j].x + qv[j].y * qv[j].y + qv[j].z * qv[j].z +
                 qv[j].w * qv[j].w;
        kk[j] += kv[j].x * kv[j].x + kv[j].y * kv[j].y + kv[j].z * kv[j].z +
                 kv[j].w * kv[j].w;
      }
    }
  }

  // reduce across the 16 pixel groups (lanes pg=0..15 within 16-lane groups)
#pragma unroll
  for (int j = 0; j < 6; ++j)
#pragma unroll
    for (int c = 0; c < 6; ++c) {
      float v = acc[j][c];
      v += __shfl_xor(v, 1);
      v += __shfl_xor(v, 2);
      v += __shfl_xor(v, 4);
      v += __shfl_xor(v, 8);
      acc[j][c] = v;
    }
#pragma unroll
  for (int j = 0; j < 6; ++j) {
    float a = qq[j], bb = kk[j];
    a += __shfl_xor(a, 1); a += __shfl_xor(a, 2);
    a += __shfl_xor(a, 4); a += __shfl_xor(a, 8);
    bb += __shfl_xor(bb, 1); bb += __shfl_xor(bb, 2);
    bb += __shfl_xor(bb, 4); bb += __shfl_xor(bb, 8);
    qq[j] = a; kk[j] = bb;
  }

  if (pg == 0) {
    float* P = Part + ((size_t)bh * NSLAB + slab) * NJOBS;
#pragma unroll
    for (int j = 0; j < 6; ++j)
#pragma unroll
      for (int c = 0; c < 6; ++c)
        P[(sr * 6 + j) * 24 + sc * 6 + c] = acc[j][c];
    if (diag) {
#pragma unroll
      for (int j = 0; j < 6; ++j) {
        P[576 + sr * 6 + j] = qq[j];
        P[600 + sc * 6 + j] = kk[j];
      }
    }
  }
}

__global__ __launch_bounds__(640) void dots_reduce(const float* __restrict__ Part,
                                                   float* __restrict__ S) {
  const int bh = blockIdx.x;
  const int job = threadIdx.x;
  if (job >= NJOBS) return;
  float s = 0.f;
  for (int i = 0; i < NSLAB; ++i)
    s += Part[((size_t)bh * NSLAB + i) * NJOBS + job];
  S[bh * NJOBS + job] = s;
}

// ---------------------------------------------------------------------------
// Normalize logits, softmax, and build per-batch fused matrix
// M_b = proj_w @ blockdiag(attn_b).  Grid (8 batches, 8 heads), 576 threads.
// ---------------------------------------------------------------------------
__global__ __launch_bounds__(576) void build_M(const float* __restrict__ S,
                                               const float* __restrict__ PW,
                                               const float* __restrict__ Temp,
                                               float* __restrict__ M) {
  const int b = blockIdx.x, h = blockIdx.y;
  const int bh = b * 8 + h;
  __shared__ float att[CH][CH];
  __shared__ float qn[CH], kn[CH];
  const int t = threadIdx.x;
  const float* Sb = S + (size_t)bh * NJOBS;

  if (t < CH) {
    qn[t] = fmaxf(sqrtf(Sb[576 + t]), 1e-12f);
    kn[t] = fmaxf(sqrtf(Sb[600 + t]), 1e-12f);
  }
  __syncthreads();
  const float temp = Temp[h];
  if (t < 576) {
    const int c = t / 24, d = t % 24;
    att[c][d] = Sb[t] / (qn[c] * kn[d]) * temp;
  }
  __syncthreads();
  if (t < CH) {
    float mx = -1e30f;
    for (int d = 0; d < CH; ++d) mx = fmaxf(mx, att[t][d]);
    float sum = 0.f;
    for (int d = 0; d < CH; ++d) {
      const float e = __expf(att[t][d] - mx);
      att[t][d] = e;
      sum += e;
    }
    const float inv = 1.f / sum;
    for (int d = 0; d < CH; ++d) att[t][d] *= inv;
  }
  __syncthreads();
  for (int i = t; i < CDIM * CH; i += 576) {
    const int o = i / CH, d = i % CH;
    float s = 0.f;
#pragma unroll
    for (int c = 0; c < CH; ++c) s += PW[o * CDIM + h * CH + c] * att[c][d];
    M[((size_t)b * CDIM + o) * CDIM + h * CH + d] = s;
  }
}

// ---------------------------------------------------------------------------

extern "C" void kernel_launch(void* const* d_in, const int* in_sizes, int n_in,
                              void* d_out, int out_size, void* d_ws, size_t ws_size,
                              hipStream_t stream) {
  const float* x_feat = (const float*)d_in[0];
  const float* y_feat = (const float*)d_in[1];
  const float* q_pw   = (const float*)d_in[2];
  const float* q_dw   = (const float*)d_in[3];
  const float* k_pw   = (const float*)d_in[4];
  const float* k_dw   = (const float*)d_in[5];
  const float* v_pw   = (const float*)d_in[6];
  const float* v_dw   = (const float*)d_in[7];
  const float* proj_w = (const float*)d_in[8];
  const float* temp   = (const float*)d_in[9];
  float* out = (float*)d_out;

  float *t0, *q, *k, *v, *part, *S, *M;
  hipGetSymbolAddress((void**)&t0,   HIP_SYMBOL(g_t0));
  hipGetSymbolAddress((void**)&q,    HIP_SYMBOL(g_q));
  hipGetSymbolAddress((void**)&k,    HIP_SYMBOL(g_k));
  hipGetSymbolAddress((void**)&v,    HIP_SYMBOL(g_v));
  hipGetSymbolAddress((void**)&part, HIP_SYMBOL(g_part));
  hipGetSymbolAddress((void**)&S,    HIP_SYMBOL(g_S));
  hipGetSymbolAddress((void**)&M,    HIP_SYMBOL(g_M));

  const dim3 ggrid(NPIX / BN, CDIM / BM, BATCH);  // (128,3,8)
  const int dwgrid = (NELEM / 4) / 256;           // 24576

  // q = dw(pw(x, q_pw), q_dw)
  pw_gemm<<<ggrid, 256, 0, stream>>>(x_feat, q_pw, 0, t0);
  dwconv<<<dwgrid, 256, 0, stream>>>(t0, q_dw, q);
  // k = dw(pw(y, k_pw), k_dw)
  pw_gemm<<<ggrid, 256, 0, stream>>>(y_feat, k_pw, 0, t0);
  dwconv<<<dwgrid, 256, 0, stream>>>(t0, k_dw, k);
  // v = dw(pw(y, v_pw), v_dw)
  pw_gemm<<<ggrid, 256, 0, stream>>>(y_feat, v_pw, 0, t0);
  dwconv<<<dwgrid, 256, 0, stream>>>(t0, v_dw, v);

  // attention gram dots + norms
  dots_partial<<<dim3(64, NSLAB), 256, 0, stream>>>(q, k, part);
  dots_reduce<<<64, 640, 0, stream>>>(part, S);

  // softmax + fold proj into per-batch matrix M_b
  build_M<<<dim3(BATCH, HEADS), 576, 0, stream>>>(S, proj_w, temp, M);

  // out = M_b @ v
  pw_gemm<<<ggrid, 256, 0, stream>>>(v, M, CDIM * CDIM, out);
}

// Round 3
// 649.443 us; speedup vs baseline: 1.5102x; 1.1388x over previous
//
#include <hip/hip_runtime.h>
#include <hip/hip_bf16.h>

#define BATCH 8
#define CDIM 192
#define HEADS 8
#define CH 24
#define HH 128
#define WW 128
#define NPIX (HH*WW)                  // 16384
#define NELEM (BATCH*CDIM*NPIX)       // 25165824
#define NP4 (NPIX/4)                  // 4096

#define NSLAB 16
#define NJOBS 624                     // 576 cross dots + 24 q self + 24 k self

typedef __attribute__((ext_vector_type(8))) short bf16x8;
typedef __attribute__((ext_vector_type(4))) float f32x4;

// ---------------------------------------------------------------------------
// One static pool, carved into buffers (96 MiB units). VF aliases T0 (t0 is
// dead after the last dwconv; VF is written after).
// ---------------------------------------------------------------------------
#define UNIT 100663296ull   // NELEM*4 bytes == 2*NELEM bf16 elements
__device__ __align__(256) unsigned char g_pool[6 * UNIT + (8u << 20)];

#define OFF_XF   (0 * UNIT)
#define OFF_YF   (1 * UNIT)
#define OFF_Q    (2 * UNIT)
#define OFF_K    (3 * UNIT)
#define OFF_V    (4 * UNIT)
#define OFF_T0   (5 * UNIT)
#define OFF_VF   (5 * UNIT)          // alias with T0
#define OFF_MISC (6 * UNIT)
#define OFF_PART (OFF_MISC)                          // 64*16*624*4 = 2555904
#define OFF_S    (OFF_MISC + 2555904ull)             // 64*624*4   = 159744
#define OFF_M    (OFF_MISC + 2555904ull + 159744ull) // 8*192*192*4 = 1179648
#define OFF_MF   (OFF_M + 1179648ull)                // hi+lo bf16  = 1179648

// round-to-nearest-even fp32 -> bf16 (bit pattern)
__device__ inline unsigned short bf_rne(float x) {
  unsigned u = __float_as_uint(x);
  unsigned r = (u + 0x7fffu + ((u >> 16) & 1u)) >> 16;
  return (unsigned short)r;
}
__device__ inline void f32_split(float x, unsigned short& h, unsigned short& l) {
  h = bf_rne(x);
  float hf = __uint_as_float(((unsigned)h) << 16);
  l = bf_rne(x - hf);
}

// ---------------------------------------------------------------------------
// Weight/M -> fragment layout.
// F_hi[(((b*12+mf)*6+ks)*64+lane)*8+j] = bf16_hi(W[b][mf*16+(lane&15)]
//                                                [ks*32+(lane>>4)*8+j])
// lo at +nb*CDIM*CDIM elements. Grid: nb*12 blocks x 64 threads.
// ---------------------------------------------------------------------------
__global__ __launch_bounds__(64) void w_to_frag(const float* __restrict__ W,
                                                unsigned short* __restrict__ F,
                                                int nb) {
  const int b = blockIdx.x / 12, mf = blockIdx.x % 12;
  const int lane = threadIdx.x;
  const int row = mf * 16 + (lane & 15);
  const size_t lo = (size_t)nb * CDIM * CDIM;
#pragma unroll
  for (int ks = 0; ks < 6; ++ks) {
    const int k0 = ks * 32 + (lane >> 4) * 8;
    const float* src = W + ((size_t)b * CDIM + row) * CDIM + k0;
    bf16x8 hv, lv;
#pragma unroll
    for (int j = 0; j < 8; ++j) {
      unsigned short h, l;
      f32_split(src[j], h, l);
      hv[j] = (short)h;
      lv[j] = (short)l;
    }
    const size_t didx = (((size_t)(blockIdx.x) * 6 + ks) * 64 + lane) * 8;
    *(bf16x8*)(F + didx) = hv;
    *(bf16x8*)(F + lo + didx) = lv;
  }
}

// ---------------------------------------------------------------------------
// Activation -> B-fragment layout.
// F_hi[((b*24+kb)*NPIX + p)*8 + j] = bf16_hi(X[b][kb*8+j][p]); lo at
// +BATCH*CDIM*NPIX elements. Grid: BATCH*24*NP4/256 blocks x 256.
// ---------------------------------------------------------------------------
__global__ __launch_bounds__(256) void x_to_frag(const float* __restrict__ X,
                                                 unsigned short* __restrict__ F) {
  const int gid = blockIdx.x * 256 + threadIdx.x;
  const int p4 = gid & (NP4 - 1);
  const int kb = (gid >> 12) % 24;
  const int b = gid / (NP4 * 24);
  const size_t lo = (size_t)BATCH * CDIM * NPIX;

  float4 v[8];
#pragma unroll
  for (int j = 0; j < 8; ++j)
    v[j] = *(const float4*)(X + ((size_t)(b * CDIM + kb * 8 + j)) * NPIX + p4 * 4);

#pragma unroll
  for (int pp = 0; pp < 4; ++pp) {
    bf16x8 hv, lv;
#pragma unroll
    for (int j = 0; j < 8; ++j) {
      const float* vv = (const float*)&v[j];
      unsigned short h, l;
      f32_split(vv[pp], h, l);
      hv[j] = (short)h;
      lv[j] = (short)l;
    }
    const size_t didx = (((size_t)(b * 24 + kb)) * NPIX + p4 * 4 + pp) * 8;
    *(bf16x8*)(F + didx) = hv;
    *(bf16x8*)(F + lo + didx) = lv;
  }
}

// ---------------------------------------------------------------------------
// MFMA GEMM: Out[b,o,p] = sum_c W[o,c] X[c,p], split-bf16 (AhBh+AhBl+AlBh).
// A (weights) in registers for whole kernel, B streamed from global in frag
// layout. No LDS, no barriers. Block 256 thr = 4 waves (2M x 2N),
// BM=64, BN=128, full K=192. Grid (128, 3, 8).
// ---------------------------------------------------------------------------
__global__ __launch_bounds__(256) void mfma_gemm(
    const unsigned short* __restrict__ BF, size_t b_lo,
    const unsigned short* __restrict__ WF, size_t w_lo,
    int w_bstride,   // 0 shared weights, CDIM*CDIM for per-batch (in elems/8*8)
    float* __restrict__ Out) {
  const int bn = blockIdx.x;  // pixel tile (128 px)
  const int bm = blockIdx.y;  // M tile (64 och)
  const int b = blockIdx.z;
  const int t = threadIdx.x;
  const int lane = t & 63, wid = t >> 6;
  const int wm = wid >> 1, wn = wid & 1;

  const size_t wbase = (size_t)b * w_bstride;
  bf16x8 Ah[2][6], Al[2][6];
#pragma unroll
  for (int mi = 0; mi < 2; ++mi) {
    const int mf = bm * 4 + wm * 2 + mi;
#pragma unroll
    for (int ks = 0; ks < 6; ++ks) {
      const size_t idx = wbase + (((size_t)(mf * 6 + ks)) * 64 + lane) * 8;
      Ah[mi][ks] = *(const bf16x8*)(WF + idx);
      Al[mi][ks] = *(const bf16x8*)(WF + w_lo + idx);
    }
  }

  f32x4 acc[2][4];
#pragma unroll
  for (int mi = 0; mi < 2; ++mi)
#pragma unroll
    for (int ni = 0; ni < 4; ++ni) acc[mi][ni] = (f32x4){0.f, 0.f, 0.f, 0.f};

  const int pcol = bn * 128 + wn * 64 + (lane & 15);
  const int kq = lane >> 4;
  const size_t bbase = (size_t)b * CDIM * NPIX;

#pragma unroll
  for (int ks = 0; ks < 6; ++ks) {
    bf16x8 Bh[4], Bl[4];
#pragma unroll
    for (int ni = 0; ni < 4; ++ni) {
      const size_t idx = bbase + (((size_t)(ks * 4 + kq)) * NPIX + pcol + ni * 16) * 8;
      Bh[ni] = *(const bf16x8*)(BF + idx);
      Bl[ni] = *(const bf16x8*)(BF + b_lo + idx);
    }
#pragma unroll
    for (int mi = 0; mi < 2; ++mi)
#pragma unroll
      for (int ni = 0; ni < 4; ++ni) {
        acc[mi][ni] = __builtin_amdgcn_mfma_f32_16x16x32_bf16(
            Ah[mi][ks], Bh[ni], acc[mi][ni], 0, 0, 0);
        acc[mi][ni] = __builtin_amdgcn_mfma_f32_16x16x32_bf16(
            Ah[mi][ks], Bl[ni], acc[mi][ni], 0, 0, 0);
        acc[mi][ni] = __builtin_amdgcn_mfma_f32_16x16x32_bf16(
            Al[mi][ks], Bh[ni], acc[mi][ni], 0, 0, 0);
      }
  }

  // C/D layout: col = lane&15 (pixel), row = (lane>>4)*4 + reg (och)
  const int ocol = bn * 128 + wn * 64 + (lane & 15);
  const int orow = bm * 64 + wm * 32 + (lane >> 4) * 4;
#pragma unroll
  for (int mi = 0; mi < 2; ++mi)
#pragma unroll
    for (int r = 0; r < 4; ++r) {
      const int och = orow + mi * 16 + r;
      float* dst = Out + ((size_t)b * CDIM + och) * NPIX + ocol;
#pragma unroll
      for (int ni = 0; ni < 4; ++ni) dst[ni * 16] = acc[mi][ni][r];
    }
}

// ---------------------------------------------------------------------------
// Depthwise 3x3 conv, zero pad (fp32 in/out, channel-major).
// ---------------------------------------------------------------------------
__global__ __launch_bounds__(256) void dwconv(const float* __restrict__ In,
                                              const float* __restrict__ Wd,
                                              float* __restrict__ Out) {
  const int idx = blockIdx.x * 256 + threadIdx.x;
  if (idx >= NELEM / 4) return;
  const int x4 = (idx & 31) * 4;
  const int y = (idx >> 5) & 127;
  const int c = (idx >> 12) % CDIM;
  const int b = idx / (32 * 128 * CDIM);

  const float* base = In + (size_t)(b * CDIM + c) * NPIX;
  float w[9];
#pragma unroll
  for (int i = 0; i < 9; ++i) w[i] = Wd[c * 9 + i];

  float acc0 = 0.f, acc1 = 0.f, acc2 = 0.f, acc3 = 0.f;
#pragma unroll
  for (int dy = 0; dy < 3; ++dy) {
    const int yy = y + dy - 1;
    if (yy < 0 || yy > 127) continue;
    const float* row = base + yy * WW;
    float vb0 = (x4 > 0) ? row[x4 - 1] : 0.f;
    const float4 m = *(const float4*)(row + x4);
    const float vb5 = (x4 + 4 < WW) ? row[x4 + 4] : 0.f;
    const float w0 = w[dy * 3 + 0], w1 = w[dy * 3 + 1], w2 = w[dy * 3 + 2];
    acc0 += w0 * vb0 + w1 * m.x + w2 * m.y;
    acc1 += w0 * m.x + w1 * m.y + w2 * m.z;
    acc2 += w0 * m.y + w1 * m.z + w2 * m.w;
    acc3 += w0 * m.z + w1 * m.w + w2 * vb5;
  }
  float4 o;
  o.x = acc0; o.y = acc1; o.z = acc2; o.w = acc3;
  *(float4*)(Out + (size_t)idx * 4) = o;
}

// ---------------------------------------------------------------------------
// Gram dots: register outer-product, no LDS. (unchanged from R2)
// ---------------------------------------------------------------------------
__global__ __launch_bounds__(256) void dots_partial(const float* __restrict__ Q,
                                                    const float* __restrict__ K,
                                                    float* __restrict__ Part) {
  const int bh = blockIdx.x;
  const int slab = blockIdx.y;
  const int b = bh >> 3, h = bh & 7;
  const int t = threadIdx.x;
  const int pg = t & 15;
  const int sb = t >> 4;
  const int sr = sb >> 2, sc = sb & 3;
  const bool diag = (sr == sc);

  const float4* qb = (const float4*)(Q + (size_t)(b * CDIM + h * CH) * NPIX);
  const float4* kb = (const float4*)(K + (size_t)(b * CDIM + h * CH) * NPIX);
  const int F_PER_SLAB = NP4 / NSLAB;
  const int NITER = F_PER_SLAB / 16;

  float acc[6][6];
#pragma unroll
  for (int j = 0; j < 6; ++j)
#pragma unroll
    for (int c = 0; c < 6; ++c) acc[j][c] = 0.f;
  float qq[6] = {0, 0, 0, 0, 0, 0};
  float kk[6] = {0, 0, 0, 0, 0, 0};

  const int f0 = slab * F_PER_SLAB + pg;
  for (int i = 0; i < NITER; ++i) {
    const int f = f0 + 16 * i;
    float4 qv[6], kv[6];
#pragma unroll
    for (int j = 0; j < 6; ++j) qv[j] = qb[(size_t)(sr * 6 + j) * NP4 + f];
#pragma unroll
    for (int j = 0; j < 6; ++j) kv[j] = kb[(size_t)(sc * 6 + j) * NP4 + f];
#pragma unroll
    for (int j = 0; j < 6; ++j)
#pragma unroll
      for (int c = 0; c < 6; ++c)
        acc[j][c] += qv[j].x * kv[c].x + qv[j].y * kv[c].y +
                     qv[j].z * kv[c].z + qv[j].w * kv[c].w;
    if (diag) {
#pragma unroll
      for (int j = 0; j < 6; ++j) {
        qq[j] += qv[j].x * qv[j].x + qv[j].y * qv[j].y + qv[j].z * qv[j].z +
                 qv[j].w * qv[j].w;
        kk[j] += kv[j].x * kv[j].x + kv[j].y * kv[j].y + kv[j].z * kv[j].z +
                 kv[j].w * kv[j].w;
      }
    }
  }

#pragma unroll
  for (int j = 0; j < 6; ++j)
#pragma unroll
    for (int c = 0; c < 6; ++c) {
      float v = acc[j][c];
      v += __shfl_xor(v, 1);
      v += __shfl_xor(v, 2);
      v += __shfl_xor(v, 4);
      v += __shfl_xor(v, 8);
      acc[j][c] = v;
    }
#pragma unroll
  for (int j = 0; j < 6; ++j) {
    float a = qq[j], bb = kk[j];
    a += __shfl_xor(a, 1); a += __shfl_xor(a, 2);
    a += __shfl_xor(a, 4); a += __shfl_xor(a, 8);
    bb += __shfl_xor(bb, 1); bb += __shfl_xor(bb, 2);
    bb += __shfl_xor(bb, 4); bb += __shfl_xor(bb, 8);
    qq[j] = a; kk[j] = bb;
  }

  if (pg == 0) {
    float* P = Part + ((size_t)bh * NSLAB + slab) * NJOBS;
#pragma unroll
    for (int j = 0; j < 6; ++j)
#pragma unroll
      for (int c = 0; c < 6; ++c)
        P[(sr * 6 + j) * 24 + sc * 6 + c] = acc[j][c];
    if (diag) {
#pragma unroll
      for (int j = 0; j < 6; ++j) {
        P[576 + sr * 6 + j] = qq[j];
        P[600 + sc * 6 + j] = kk[j];
      }
    }
  }
}

__global__ __launch_bounds__(640) void dots_reduce(const float* __restrict__ Part,
                                                   float* __restrict__ S) {
  const int bh = blockIdx.x;
  const int job = threadIdx.x;
  if (job >= NJOBS) return;
  float s = 0.f;
  for (int i = 0; i < NSLAB; ++i)
    s += Part[((size_t)bh * NSLAB + i) * NJOBS + job];
  S[bh * NJOBS + job] = s;
}

// ---------------------------------------------------------------------------
// Normalize, softmax, fold proj: M_b = proj_w @ blockdiag(attn_b).
// ---------------------------------------------------------------------------
__global__ __launch_bounds__(576) void build_M(const float* __restrict__ S,
                                               const float* __restrict__ PW,
                                               const float* __restrict__ Temp,
                                               float* __restrict__ M) {
  const int b = blockIdx.x, h = blockIdx.y;
  const int bh = b * 8 + h;
  __shared__ float att[CH][CH];
  __shared__ float qn[CH], kn[CH];
  const int t = threadIdx.x;
  const float* Sb = S + (size_t)bh * NJOBS;

  if (t < CH) {
    qn[t] = fmaxf(sqrtf(Sb[576 + t]), 1e-12f);
    kn[t] = fmaxf(sqrtf(Sb[600 + t]), 1e-12f);
  }
  __syncthreads();
  const float temp = Temp[h];
  if (t < 576) {
    const int c = t / 24, d = t % 24;
    att[c][d] = Sb[t] / (qn[c] * kn[d]) * temp;
  }
  __syncthreads();
  if (t < CH) {
    float mx = -1e30f;
    for (int d = 0; d < CH; ++d) mx = fmaxf(mx, att[t][d]);
    float sum = 0.f;
    for (int d = 0; d < CH; ++d) {
      const float e = __expf(att[t][d] - mx);
      att[t][d] = e;
      sum += e;
    }
    const float inv = 1.f / sum;
    for (int d = 0; d < CH; ++d) att[t][d] *= inv;
  }
  __syncthreads();
  for (int i = t; i < CDIM * CH; i += 576) {
    const int o = i / CH, d = i % CH;
    float s = 0.f;
#pragma unroll
    for (int c = 0; c < CH; ++c) s += PW[o * CDIM + h * CH + c] * att[c][d];
    M[((size_t)b * CDIM + o) * CDIM + h * CH + d] = s;
  }
}

// ---------------------------------------------------------------------------

extern "C" void kernel_launch(void* const* d_in, const int* in_sizes, int n_in,
                              void* d_out, int out_size, void* d_ws, size_t ws_size,
                              hipStream_t stream) {
  const float* x_feat = (const float*)d_in[0];
  const float* y_feat = (const float*)d_in[1];
  const float* q_pw   = (const float*)d_in[2];
  const float* q_dw   = (const float*)d_in[3];
  const float* k_pw   = (const float*)d_in[4];
  const float* k_dw   = (const float*)d_in[5];
  const float* v_pw   = (const float*)d_in[6];
  const float* v_dw   = (const float*)d_in[7];
  const float* proj_w = (const float*)d_in[8];
  const float* temp   = (const float*)d_in[9];
  float* out = (float*)d_out;

  unsigned char* pool;
  hipGetSymbolAddress((void**)&pool, HIP_SYMBOL(g_pool));
  unsigned short* XF = (unsigned short*)(pool + OFF_XF);
  unsigned short* YF = (unsigned short*)(pool + OFF_YF);
  float* q  = (float*)(pool + OFF_Q);
  float* k  = (float*)(pool + OFF_K);
  float* v  = (float*)(pool + OFF_V);
  float* t0 = (float*)(pool + OFF_T0);
  unsigned short* VF = (unsigned short*)(pool + OFF_VF);
  float* part = (float*)(pool + OFF_PART);
  float* S    = (float*)(pool + OFF_S);
  float* M    = (float*)(pool + OFF_M);
  unsigned short* MF = (unsigned short*)(pool + OFF_MF);

  // Small per-GEMM weight frag buffers live in MISC tail? No — weights go in
  // dedicated slots right after MF (3 x 2*CDIM*CDIM bf16 = 442368 B total).
  unsigned short* WQF = MF + 2ull * 8 * CDIM * CDIM;        // after MF hi+lo
  unsigned short* WKF = WQF + 2ull * CDIM * CDIM;
  unsigned short* WVF = WKF + 2ull * CDIM * CDIM;

  const size_t act_lo = (size_t)BATCH * CDIM * NPIX;   // b-frag lo offset
  const size_t w1_lo  = (size_t)1 * CDIM * CDIM;       // shared-weight lo off
  const size_t w8_lo  = (size_t)8 * CDIM * CDIM;       // per-batch M lo off

  const dim3 ggrid(NPIX / 128, 3, BATCH);
  const int fgrid = (BATCH * 24 * NP4) / 256;          // 3072
  const int dwgrid = (NELEM / 4) / 256;

  // weight conversions (tiny)
  w_to_frag<<<12, 64, 0, stream>>>(q_pw, WQF, 1);
  w_to_frag<<<12, 64, 0, stream>>>(k_pw, WKF, 1);
  w_to_frag<<<12, 64, 0, stream>>>(v_pw, WVF, 1);
  // activation conversions
  x_to_frag<<<fgrid, 256, 0, stream>>>(x_feat, XF);
  x_to_frag<<<fgrid, 256, 0, stream>>>(y_feat, YF);

  // q/k/v = dw(pw(...))
  mfma_gemm<<<ggrid, 256, 0, stream>>>(XF, act_lo, WQF, w1_lo, 0, t0);
  dwconv<<<dwgrid, 256, 0, stream>>>(t0, q_dw, q);
  mfma_gemm<<<ggrid, 256, 0, stream>>>(YF, act_lo, WKF, w1_lo, 0, t0);
  dwconv<<<dwgrid, 256, 0, stream>>>(t0, k_dw, k);
  mfma_gemm<<<ggrid, 256, 0, stream>>>(YF, act_lo, WVF, w1_lo, 0, t0);
  dwconv<<<dwgrid, 256, 0, stream>>>(t0, v_dw, v);

  // attention gram + softmax + proj fold
  dots_partial<<<dim3(64, NSLAB), 256, 0, stream>>>(q, k, part);
  dots_reduce<<<64, 640, 0, stream>>>(part, S);
  build_M<<<dim3(BATCH, HEADS), 576, 0, stream>>>(S, proj_w, temp, M);
  w_to_frag<<<8 * 12, 64, 0, stream>>>(M, MF, 8);

  // V to frag (t0 dead now; VF aliases it)
  x_to_frag<<<fgrid, 256, 0, stream>>>(v, VF);

  // out = M_b @ v
  mfma_gemm<<<ggrid, 256, 0, stream>>>(VF, act_lo, MF, w8_lo, CDIM * CDIM, out);
}